// Round 9
// baseline (113.505 us; speedup 1.0000x reference)
//
#include <hip/hip_runtime.h>

// SememeEmbeddingKNN, 2-kernel decomposition.
//   emb      [V=50257, H=1024] f32   (206 MB -> L3-resident)
//   word_ids [L=256, W=16]     i32
//   sem_ids  [L=256, W=16, S=32] i32
//   out      [L, H] f32
//
// R8 -> R9: R8's __launch_bounds__(256,8) pinned VGPR to 16 -> the 5 float4
// loads serialized (2.8 TB/s). Same geometry (wave per (b,quad,quarter),
// 131072 waves, 5 independent float4 loads, 670 MB logical), natural VGPR
// (~48-64) so all 5 loads stay in flight. BC: stage-2 gather unroll 4 -> 8
// (more outstanding loads; only 256 blocks so per-wave MLP is the lever).

#define HDIM 1024
#define SNUM 32
#define WNUM 16
#define KNN  3

// ---------------- Phase A: partial distances (wave per b,quad,quarter) ----
__global__ __launch_bounds__(256) void knn_dist_kernel(
    const float* __restrict__ emb,
    const int*   __restrict__ word_ids,
    const int*   __restrict__ sem_ids,
    float*       __restrict__ dist_part,   // [4][nj]
    int nj)
{
    const int wave = threadIdx.x >> 6;     // quarter 0..3
    const int lane = threadIdx.x & 63;
    const int blk  = blockIdx.x;           // b*8 + quad
    const int b    = blk >> 3;
    const int quad = blk & 7;

    const int base_s  = b * SNUM + quad * 4;
    const int col     = wave * 256 + 4 * lane;

    const int  wid = word_ids[b];
    const int4 sa  = *(const int4*)(sem_ids + base_s);   // block-uniform

    // 5 independent float4 loads (word first).
    const float4 w  = *(const float4*)(emb + (size_t)wid  * HDIM + col);
    const float4 s0 = *(const float4*)(emb + (size_t)sa.x * HDIM + col);
    const float4 s1 = *(const float4*)(emb + (size_t)sa.y * HDIM + col);
    const float4 s2 = *(const float4*)(emb + (size_t)sa.z * HDIM + col);
    const float4 s3 = *(const float4*)(emb + (size_t)sa.w * HDIM + col);

    float d[4];
    {
        const float dx = s0.x - w.x, dy = s0.y - w.y, dz = s0.z - w.z, dw = s0.w - w.w;
        d[0] = (dx * dx + dy * dy) + (dz * dz + dw * dw);
    }
    {
        const float dx = s1.x - w.x, dy = s1.y - w.y, dz = s1.z - w.z, dw = s1.w - w.w;
        d[1] = (dx * dx + dy * dy) + (dz * dz + dw * dw);
    }
    {
        const float dx = s2.x - w.x, dy = s2.y - w.y, dz = s2.z - w.z, dw = s2.w - w.w;
        d[2] = (dx * dx + dy * dy) + (dz * dz + dw * dw);
    }
    {
        const float dx = s3.x - w.x, dy = s3.y - w.y, dz = s3.z - w.z, dw = s3.w - w.w;
        d[3] = (dx * dx + dy * dy) + (dz * dz + dw * dw);
    }

    // 4 independent 6-deep butterfly chains (pipelined).
    #pragma unroll
    for (int k = 0; k < 4; ++k) {
        #pragma unroll
        for (int off = 32; off >= 1; off >>= 1)
            d[k] += __shfl_xor(d[k], off, 64);
    }

    if (lane == 0)
        *(float4*)(dist_part + (size_t)wave * nj + base_s) =
            make_float4(d[0], d[1], d[2], d[3]);
}

// ------------- Phase BC: select (top-3) + gather/accumulate, fused --------
__global__ __launch_bounds__(256) void knn_outsel_kernel(
    const float* __restrict__ emb,
    const float* __restrict__ dist_part,   // [4][nj]
    const int*   __restrict__ word_ids,
    const int*   __restrict__ sem_ids,
    float*       __restrict__ out,
    int nj)
{
    const int l = blockIdx.x;
    const int t = threadIdx.x;

    __shared__ int s_ids[WNUM * 4];

    // Stage 1: threads 0..15 each select for one word.
    if (t < WNUM) {
        const int b = l * WNUM + t;
        float4 acc[8];
        #pragma unroll
        for (int i = 0; i < 8; ++i) acc[i] = make_float4(0.f, 0.f, 0.f, 0.f);
        #pragma unroll
        for (int q = 0; q < 4; ++q) {
            const float4* p = (const float4*)(dist_part + (size_t)q * nj + b * SNUM);
            #pragma unroll
            for (int i = 0; i < 8; ++i) {
                const float4 v = p[i];
                acc[i].x += v.x; acc[i].y += v.y; acc[i].z += v.z; acc[i].w += v.w;
            }
        }
        float dl[SNUM];
        #pragma unroll
        for (int i = 0; i < 8; ++i) {
            dl[4 * i + 0] = acc[i].x;
            dl[4 * i + 1] = acc[i].y;
            dl[4 * i + 2] = acc[i].z;
            dl[4 * i + 3] = acc[i].w;
        }
        // Top-3 descending; strict '>' keeps earliest index (= jax top_k).
        unsigned chosen = 0;
        #pragma unroll
        for (int k = 0; k < KNN; ++k) {
            float best = -1.0f;
            int   bi   = 0;
            #pragma unroll
            for (int s = 0; s < SNUM; ++s) {
                if (!((chosen >> s) & 1u) && dl[s] > best) { best = dl[s]; bi = s; }
            }
            chosen |= (1u << bi);
            s_ids[t * 4 + k] = sem_ids[b * SNUM + bi];
        }
        s_ids[t * 4 + 3] = word_ids[b];
    }
    __syncthreads();

    // Stage 2: all 256 threads gather float4 at h = 4t; unroll 8 -> 32
    // outstanding loads per thread-iteration.
    const float third = 1.0f / 3.0f;
    float ax = 0.f, ay = 0.f, az = 0.f, aw = 0.f;
    #pragma unroll 8
    for (int w = 0; w < WNUM; ++w) {
        const float4 e0 = *(const float4*)(emb + (size_t)s_ids[w * 4 + 0] * HDIM + 4 * t);
        const float4 e1 = *(const float4*)(emb + (size_t)s_ids[w * 4 + 1] * HDIM + 4 * t);
        const float4 e2 = *(const float4*)(emb + (size_t)s_ids[w * 4 + 2] * HDIM + 4 * t);
        const float4 ew = *(const float4*)(emb + (size_t)s_ids[w * 4 + 3] * HDIM + 4 * t);
        ax += (e0.x + e1.x + e2.x) * third + ew.x;
        ay += (e0.y + e1.y + e2.y) * third + ew.y;
        az += (e0.z + e1.z + e2.z) * third + ew.z;
        aw += (e0.w + e1.w + e2.w) * third + ew.w;
    }
    const float scale = 0.5f / 16.0f;
    *(float4*)(out + (size_t)l * HDIM + 4 * t) =
        make_float4(ax * scale, ay * scale, az * scale, aw * scale);
}

extern "C" void kernel_launch(void* const* d_in, const int* in_sizes, int n_in,
                              void* d_out, int out_size, void* d_ws, size_t ws_size,
                              hipStream_t stream) {
    const float* emb  = (const float*)d_in[0];
    const int*   wids = (const int*)d_in[1];
    const int*   sids = (const int*)d_in[2];
    float*       out  = (float*)d_out;

    const int nb = in_sizes[1];          // L*W = 4096
    const int nj = in_sizes[2];          // L*W*S = 131072
    const int L  = out_size / HDIM;      // 256

    float* dist_part = (float*)d_ws;     // 4*nj floats (2 MB)

    knn_dist_kernel<<<dim3(nb * 8), dim3(256), 0, stream>>>(emb, wids, sids, dist_part, nj);
    knn_outsel_kernel<<<dim3(L), dim3(256), 0, stream>>>(emb, dist_part, wids, sids, out, nj);
}

// Round 10
// 113.199 us; speedup vs baseline: 1.0027x; 1.0027x over previous
//
#include <hip/hip_runtime.h>

// SememeEmbeddingKNN, 2-kernel decomposition.
//   emb      [V=50257, H=1024] f32   (206 MB -> L3-resident)
//   word_ids [L=256, W=16]     i32
//   sem_ids  [L=256, W=16, S=32] i32
//   out      [L, H] f32
//
// R9 -> R10: R9 proved the allocator serializes the 5 gathers (VGPR=20,
// 2.8 TB/s) - it reuses one float4's regs for the next load. Fix: empty
// asm volatile consuming all 5 loaded vectors BEFORE any arithmetic ->
// dataflow forces 5 back-to-back global_load_dwordx4 + single waitcnt,
// all 5 results live (VGPR >= 40). Geometry unchanged from R9:
// wave per (b,quad,quarter), 131072 waves, 670 MB logical, the 4 waves of
// a block cover the 4 quarters of the SAME quad (block footprint = 5 rows).
// BC unchanged (R6 version): select (strict '>', earliest index on ties =
// jax top_k) fused with float4 gather/accumulate. No atomics, no memset.

#define HDIM 1024
#define SNUM 32
#define WNUM 16
#define KNN  3

typedef float f32x4 __attribute__((ext_vector_type(4)));

// ---------------- Phase A: partial distances (wave per b,quad,quarter) ----
__global__ __launch_bounds__(256) void knn_dist_kernel(
    const float* __restrict__ emb,
    const int*   __restrict__ word_ids,
    const int*   __restrict__ sem_ids,
    float*       __restrict__ dist_part,   // [4][nj]
    int nj)
{
    const int wave = threadIdx.x >> 6;     // quarter 0..3
    const int lane = threadIdx.x & 63;
    const int blk  = blockIdx.x;           // b*8 + quad
    const int b    = blk >> 3;
    const int quad = blk & 7;

    const int base_s  = b * SNUM + quad * 4;
    const int col     = wave * 256 + 4 * lane;

    const int  wid = word_ids[b];
    const int4 sa  = *(const int4*)(sem_ids + base_s);   // block-uniform

    // 5 independent float4 gathers; asm liveness barrier forces all 5 to be
    // issued and simultaneously live before any use (defeats the allocator's
    // occupancy-first serialization seen in R9: VGPR=20, loads serialized).
    f32x4 w  = *(const f32x4*)(emb + (size_t)wid  * HDIM + col);
    f32x4 s0 = *(const f32x4*)(emb + (size_t)sa.x * HDIM + col);
    f32x4 s1 = *(const f32x4*)(emb + (size_t)sa.y * HDIM + col);
    f32x4 s2 = *(const f32x4*)(emb + (size_t)sa.z * HDIM + col);
    f32x4 s3 = *(const f32x4*)(emb + (size_t)sa.w * HDIM + col);
    asm volatile("" : "+v"(w), "+v"(s0), "+v"(s1), "+v"(s2), "+v"(s3));

    float d[4];
    {
        const f32x4 df = s0 - w;
        d[0] = (df.x * df.x + df.y * df.y) + (df.z * df.z + df.w * df.w);
    }
    {
        const f32x4 df = s1 - w;
        d[1] = (df.x * df.x + df.y * df.y) + (df.z * df.z + df.w * df.w);
    }
    {
        const f32x4 df = s2 - w;
        d[2] = (df.x * df.x + df.y * df.y) + (df.z * df.z + df.w * df.w);
    }
    {
        const f32x4 df = s3 - w;
        d[3] = (df.x * df.x + df.y * df.y) + (df.z * df.z + df.w * df.w);
    }

    // 4 independent 6-deep butterfly chains (pipelined).
    #pragma unroll
    for (int k = 0; k < 4; ++k) {
        #pragma unroll
        for (int off = 32; off >= 1; off >>= 1)
            d[k] += __shfl_xor(d[k], off, 64);
    }

    if (lane == 0)
        *(float4*)(dist_part + (size_t)wave * nj + base_s) =
            make_float4(d[0], d[1], d[2], d[3]);
}

// ------------- Phase BC: select (top-3) + gather/accumulate, fused --------
__global__ __launch_bounds__(256) void knn_outsel_kernel(
    const float* __restrict__ emb,
    const float* __restrict__ dist_part,   // [4][nj]
    const int*   __restrict__ word_ids,
    const int*   __restrict__ sem_ids,
    float*       __restrict__ out,
    int nj)
{
    const int l = blockIdx.x;
    const int t = threadIdx.x;

    __shared__ int s_ids[WNUM * 4];

    // Stage 1: threads 0..15 each select for one word.
    if (t < WNUM) {
        const int b = l * WNUM + t;
        float4 acc[8];
        #pragma unroll
        for (int i = 0; i < 8; ++i) acc[i] = make_float4(0.f, 0.f, 0.f, 0.f);
        #pragma unroll
        for (int q = 0; q < 4; ++q) {
            const float4* p = (const float4*)(dist_part + (size_t)q * nj + b * SNUM);
            #pragma unroll
            for (int i = 0; i < 8; ++i) {
                const float4 v = p[i];
                acc[i].x += v.x; acc[i].y += v.y; acc[i].z += v.z; acc[i].w += v.w;
            }
        }
        float dl[SNUM];
        #pragma unroll
        for (int i = 0; i < 8; ++i) {
            dl[4 * i + 0] = acc[i].x;
            dl[4 * i + 1] = acc[i].y;
            dl[4 * i + 2] = acc[i].z;
            dl[4 * i + 3] = acc[i].w;
        }
        // Top-3 descending; strict '>' keeps earliest index (= jax top_k).
        unsigned chosen = 0;
        #pragma unroll
        for (int k = 0; k < KNN; ++k) {
            float best = -1.0f;
            int   bi   = 0;
            #pragma unroll
            for (int s = 0; s < SNUM; ++s) {
                if (!((chosen >> s) & 1u) && dl[s] > best) { best = dl[s]; bi = s; }
            }
            chosen |= (1u << bi);
            s_ids[t * 4 + k] = sem_ids[b * SNUM + bi];
        }
        s_ids[t * 4 + 3] = word_ids[b];
    }
    __syncthreads();

    // Stage 2: all 256 threads gather float4 at h = 4t.
    const float third = 1.0f / 3.0f;
    float ax = 0.f, ay = 0.f, az = 0.f, aw = 0.f;
    #pragma unroll 8
    for (int w = 0; w < WNUM; ++w) {
        const float4 e0 = *(const float4*)(emb + (size_t)s_ids[w * 4 + 0] * HDIM + 4 * t);
        const float4 e1 = *(const float4*)(emb + (size_t)s_ids[w * 4 + 1] * HDIM + 4 * t);
        const float4 e2 = *(const float4*)(emb + (size_t)s_ids[w * 4 + 2] * HDIM + 4 * t);
        const float4 ew = *(const float4*)(emb + (size_t)s_ids[w * 4 + 3] * HDIM + 4 * t);
        ax += (e0.x + e1.x + e2.x) * third + ew.x;
        ay += (e0.y + e1.y + e2.y) * third + ew.y;
        az += (e0.z + e1.z + e2.z) * third + ew.z;
        aw += (e0.w + e1.w + e2.w) * third + ew.w;
    }
    const float scale = 0.5f / 16.0f;
    *(float4*)(out + (size_t)l * HDIM + 4 * t) =
        make_float4(ax * scale, ay * scale, az * scale, aw * scale);
}

extern "C" void kernel_launch(void* const* d_in, const int* in_sizes, int n_in,
                              void* d_out, int out_size, void* d_ws, size_t ws_size,
                              hipStream_t stream) {
    const float* emb  = (const float*)d_in[0];
    const int*   wids = (const int*)d_in[1];
    const int*   sids = (const int*)d_in[2];
    float*       out  = (float*)d_out;

    const int nb = in_sizes[1];          // L*W = 4096
    const int nj = in_sizes[2];          // L*W*S = 131072
    const int L  = out_size / HDIM;      // 256

    float* dist_part = (float*)d_ws;     // 4*nj floats (2 MB)

    knn_dist_kernel<<<dim3(nb * 8), dim3(256), 0, stream>>>(emb, wids, sids, dist_part, nj);
    knn_outsel_kernel<<<dim3(L), dim3(256), 0, stream>>>(emb, dist_part, wids, sids, out, nj);
}

// Round 11
// 91.882 us; speedup vs baseline: 1.2353x; 1.2320x over previous
//
#include <hip/hip_runtime.h>

// SememeEmbeddingKNN, 2-kernel decomposition with table-chunked phase A.
//   emb      [V=50257, H=1024] f32   (206 MB table)
//   word_ids [L=256, W=16]     i32
//   sem_ids  [L=256, W=16, S=32] i32
//   out      [L, H] f32
//
// R10 -> R11: warm counters showed phase A fetches 331 MB from HBM at
// 2.85 TB/s every dispatch (= entire kernel time). The table + scattered
// re-reads thrash L3 (working set ~220 MB vs 256 MB). Fix: 2-pass CHUNKING -
// pass p only computes sememes with sid in half p of the table, so per-pass
// working set (103 MB chunk + 16 MB words) is L3-resident and re-touches hit
// L3. Out-of-chunk lanes load the block's own (L1-warm) word row as a dummy
// so the 8 gathers stay unconditional and dense; only in-chunk dists stored.
// Kernel structure is otherwise R6's best-measured phase A (LDS word
// staging, wave per (b,octet), block per (b,quarter)).
// BC: select (strict '>', earliest index on ties = jax top_k) fused with
// float4 gather/accumulate. No atomics, no memset.

#define HDIM 1024
#define SNUM 32
#define WNUM 16
#define KNN  3

// ------- Phase A: chunked partial distances (wave per b,octet,quarter) ----
__global__ __launch_bounds__(256) void knn_dist_chunk_kernel(
    const float* __restrict__ emb,
    const int*   __restrict__ word_ids,
    const int*   __restrict__ sem_ids,
    float*       __restrict__ dist_part,   // [4][nj]
    int nj, int lo, int hi)
{
    const int wave = threadIdx.x >> 6;     // octet 0..3
    const int lane = threadIdx.x & 63;
    const int blk  = blockIdx.x;           // b*4 + quarter
    const int b    = blk >> 2;
    const int quarter = blk & 3;

    __shared__ float s_w[256];

    const int wid = word_ids[b];
    // Coop word-quarter load: 1 float/thread (also warms L1 for dummy loads).
    s_w[threadIdx.x] = emb[(size_t)wid * HDIM + quarter * 256 + threadIdx.x];

    const int base_s = b * SNUM + wave * 8;
    const int col    = quarter * 256 + 4 * lane;

    const int4 sa = *(const int4*)(sem_ids + base_s);
    const int4 sb = *(const int4*)(sem_ids + base_s + 4);

    __syncthreads();
    const float4 w = *(const float4*)(s_w + 4 * lane);

    const int sids[8] = {sa.x, sa.y, sa.z, sa.w, sb.x, sb.y, sb.z, sb.w};
    bool  inch[8];
    float4 sv[8];
    #pragma unroll
    for (int k = 0; k < 8; ++k) {
        inch[k] = (sids[k] >= lo) & (sids[k] < hi);
        const int sid_eff = inch[k] ? sids[k] : wid;   // dummy -> L1-warm row
        sv[k] = *(const float4*)(emb + (size_t)sid_eff * HDIM + col);
    }

    float d[8];
    #pragma unroll
    for (int k = 0; k < 8; ++k) {
        const float dx = sv[k].x - w.x;
        const float dy = sv[k].y - w.y;
        const float dz = sv[k].z - w.z;
        const float dw = sv[k].w - w.w;
        d[k] = (dx * dx + dy * dy) + (dz * dz + dw * dw);
    }

    // 8 independent 6-deep butterfly chains (pipelined).
    #pragma unroll
    for (int k = 0; k < 8; ++k) {
        #pragma unroll
        for (int off = 32; off >= 1; off >>= 1)
            d[k] += __shfl_xor(d[k], off, 64);
    }

    if (lane == 0) {
        float* p = dist_part + (size_t)quarter * nj + base_s;
        #pragma unroll
        for (int k = 0; k < 8; ++k)
            if (inch[k]) p[k] = d[k];
    }
}

// ------------- Phase BC: select (top-3) + gather/accumulate, fused --------
__global__ __launch_bounds__(256) void knn_outsel_kernel(
    const float* __restrict__ emb,
    const float* __restrict__ dist_part,   // [4][nj]
    const int*   __restrict__ word_ids,
    const int*   __restrict__ sem_ids,
    float*       __restrict__ out,
    int nj)
{
    const int l = blockIdx.x;
    const int t = threadIdx.x;

    __shared__ int s_ids[WNUM * 4];

    // Stage 1: threads 0..15 each select for one word.
    if (t < WNUM) {
        const int b = l * WNUM + t;
        float4 acc[8];
        #pragma unroll
        for (int i = 0; i < 8; ++i) acc[i] = make_float4(0.f, 0.f, 0.f, 0.f);
        #pragma unroll
        for (int q = 0; q < 4; ++q) {
            const float4* p = (const float4*)(dist_part + (size_t)q * nj + b * SNUM);
            #pragma unroll
            for (int i = 0; i < 8; ++i) {
                const float4 v = p[i];
                acc[i].x += v.x; acc[i].y += v.y; acc[i].z += v.z; acc[i].w += v.w;
            }
        }
        float dl[SNUM];
        #pragma unroll
        for (int i = 0; i < 8; ++i) {
            dl[4 * i + 0] = acc[i].x;
            dl[4 * i + 1] = acc[i].y;
            dl[4 * i + 2] = acc[i].z;
            dl[4 * i + 3] = acc[i].w;
        }
        // Top-3 descending; strict '>' keeps earliest index (= jax top_k).
        unsigned chosen = 0;
        #pragma unroll
        for (int k = 0; k < KNN; ++k) {
            float best = -1.0f;
            int   bi   = 0;
            #pragma unroll
            for (int s = 0; s < SNUM; ++s) {
                if (!((chosen >> s) & 1u) && dl[s] > best) { best = dl[s]; bi = s; }
            }
            chosen |= (1u << bi);
            s_ids[t * 4 + k] = sem_ids[b * SNUM + bi];
        }
        s_ids[t * 4 + 3] = word_ids[b];
    }
    __syncthreads();

    // Stage 2: all 256 threads gather float4 at h = 4t.
    const float third = 1.0f / 3.0f;
    float ax = 0.f, ay = 0.f, az = 0.f, aw = 0.f;
    #pragma unroll 8
    for (int w = 0; w < WNUM; ++w) {
        const float4 e0 = *(const float4*)(emb + (size_t)s_ids[w * 4 + 0] * HDIM + 4 * t);
        const float4 e1 = *(const float4*)(emb + (size_t)s_ids[w * 4 + 1] * HDIM + 4 * t);
        const float4 e2 = *(const float4*)(emb + (size_t)s_ids[w * 4 + 2] * HDIM + 4 * t);
        const float4 ew = *(const float4*)(emb + (size_t)s_ids[w * 4 + 3] * HDIM + 4 * t);
        ax += (e0.x + e1.x + e2.x) * third + ew.x;
        ay += (e0.y + e1.y + e2.y) * third + ew.y;
        az += (e0.z + e1.z + e2.z) * third + ew.z;
        aw += (e0.w + e1.w + e2.w) * third + ew.w;
    }
    const float scale = 0.5f / 16.0f;
    *(float4*)(out + (size_t)l * HDIM + 4 * t) =
        make_float4(ax * scale, ay * scale, az * scale, aw * scale);
}

extern "C" void kernel_launch(void* const* d_in, const int* in_sizes, int n_in,
                              void* d_out, int out_size, void* d_ws, size_t ws_size,
                              hipStream_t stream) {
    const float* emb  = (const float*)d_in[0];
    const int*   wids = (const int*)d_in[1];
    const int*   sids = (const int*)d_in[2];
    float*       out  = (float*)d_out;

    const int nb = in_sizes[1];          // L*W = 4096
    const int nj = in_sizes[2];          // L*W*S = 131072
    const int L  = out_size / HDIM;      // 256
    const int V  = in_sizes[0] / HDIM;   // 50257
    const int MID = V / 2;

    float* dist_part = (float*)d_ws;     // 4*nj floats (2 MB)

    // Pass 0: sids in [0, MID); pass 1: sids in [MID, V). In-order stream
    // serializes the passes, time-partitioning L3 between the two chunks.
    knn_dist_chunk_kernel<<<dim3(nb * 4), dim3(256), 0, stream>>>(
        emb, wids, sids, dist_part, nj, 0, MID);
    knn_dist_chunk_kernel<<<dim3(nb * 4), dim3(256), 0, stream>>>(
        emb, wids, sids, dist_part, nj, MID, V);
    knn_outsel_kernel<<<dim3(L), dim3(256), 0, stream>>>(
        emb, dist_part, wids, sids, out, nj);
}